// Round 1
// baseline (108.026 us; speedup 1.0000x reference)
//
#include <hip/hip_runtime.h>

#define NB 4
#define NC 32
#define NH 32
#define NW 32
#define KK 288                   // 32*3*3 patch length
#define PLANE (NB*NC*NH*NW)      // 131072 elements per plane
#define CHALF 16                 // channels per block (split reduction)

__device__ __forceinline__ float s3(float v) { return sqrtf(sqrtf(sqrtf(v))); }

// Zero-mean weight rows; write padded float4 layout [co][c][r] = {w(r,0),w(r,1),w(r,2),pad}.
__global__ __launch_bounds__(256) void prep_weights_k(
        const float* __restrict__ w1, const float* __restrict__ w2,
        float* __restrict__ wf1, float* __restrict__ wf2)
{
    const int row = blockIdx.x;                   // 0..63
    const float* src = (row < NC) ? w1 : w2;
    float* dst = (row < NC) ? wf1 : wf2;
    const int co = row & (NC - 1);
    const int tid = threadIdx.x;
    __shared__ float red[256];
    const float a = src[co*KK + tid];                              // tid < 256 < 288
    const float b = (tid + 256 < KK) ? src[co*KK + tid + 256] : 0.0f;
    red[tid] = a + b;
    __syncthreads();
    for (int s = 128; s > 0; s >>= 1) {
        if (tid < s) red[tid] += red[tid + s];
        __syncthreads();
    }
    const float mean = red[0] * (1.0f / (float)KK);
    // element e -> float offset co*384 + (c*3+r)*4 + kw, where e = c*9 + r*3 + kw
    {
        const int e = tid, c = e / 9, r9 = e - c*9, r = r9 / 3, kw = r9 - r*3;
        dst[co*384 + ((c*3 + r) << 2) + kw] = a - mean;
    }
    if (tid + 256 < KK) {
        const int e = tid + 256, c = e / 9, r9 = e - c*9, r = r9 / 3, kw = r9 - r*3;
        dst[co*384 + ((c*3 + r) << 2) + kw] = b - mean;
    }
}

// Half-channel norm-dist conv. Block = 32(w) x 8(ty). Each thread computes ONE pixel
// for TWO output channels (co = cog*16+ty and +8) so every patch ds_read feeds 18 taps.
// Grid = (h=32, cog*2+chalf=4, b=4) -> 512 blocks.
// STAGE1: stages x/l/u directly. STAGE2: stages (p0+p1)^(1/8) from conv1 partials.
// Both write partial (pre-root) sums to pY/pL/pU at [chalf*PLANE + o].
template<bool STAGE2>
__global__ __launch_bounds__(256, 2) void normdist_conv_k(
    const float* __restrict__ sy,     // stage1: x plane | stage2: conv1 Y partials [2][PLANE]
    const float* __restrict__ sl,
    const float* __restrict__ su,
    const float* __restrict__ wf,     // prepped weights, float4 [co][c][r]
    float* __restrict__ pY, float* __restrict__ pL, float* __restrict__ pU)
{
    const int h     = blockIdx.x;
    const int cog   = blockIdx.y >> 1;
    const int chalf = blockIdx.y & 1;
    const int ch0   = chalf * CHALF;
    const int b     = blockIdx.z;
    const int tx    = threadIdx.x;
    const int ty    = threadIdx.y;
    const int tid   = ty * 32 + tx;

    // Patch halo, xlu-interleaved: [c<16][r<3][col<34] float4 (w unused). 26112 B.
    __shared__ float4 sP[CHALF*3*34];

    for (int i = tid; i < CHALF*3*34; i += 256) {
        const int c   = i / 102;
        const int rem = i - c*102;
        const int r   = rem / 34;
        const int col = rem - r*34;
        const int gh  = h + r - 1;
        const int gw  = col - 1;
        float vx = 0.0f, vl = 0.0f, vu = 0.0f;
        if ((unsigned)gh < NH && (unsigned)gw < NW) {
            const int g = ((b*NC + ch0 + c)*NH + gh)*NW + gw;
            if (STAGE2) {   // combine conv1 halves + eighth-root (relu no-op: >=0)
                vx = s3(sy[g] + sy[PLANE + g]);
                vl = s3(sl[g] + sl[PLANE + g]);
                vu = s3(su[g] + su[PLANE + g]);
            } else {
                vx = sy[g]; vl = sl[g]; vu = su[g];
            }
        }
        sP[i] = make_float4(vx, vl, vu, 0.0f);
    }
    __syncthreads();

    const int co0 = cog*16 + ty;        // {0..7, 16..23}
    const int co1 = co0 + 8;            // {8..15, 24..31}
    const float4* wbA = (const float4*)wf + (co0*NC + ch0)*3;
    const float4* wbB = (const float4*)wf + (co1*NC + ch0)*3;

    float aY0 = 0.0f, aL0 = 0.0f, aU0 = 0.0f;
    float aY1 = 0.0f, aL1 = 0.0f, aU1 = 0.0f;

    auto tap = [&](float wv, float4 p, float& accY, float& accL, float& accU) {
        const float d  = p.x - wv;          // y: |d|^8 = ((d^2)^2)^2
        const float d2 = d*d, d4 = d2*d2;
        accY = fmaf(d4, d4, accY);
        const float a  = p.y - wv;          // dl: max(a, nb, 0)^8
        const float nb = wv - p.z;
        const float m  = fmaxf(fmaxf(a, nb), 0.0f);
        const float m2 = m*m, m4 = m2*m2;
        accL = fmaf(m4, m4, accL);
        const float a2 = a*a, q2 = nb*nb;   // du: max(a^2, nb^2)^4
        const float mm2 = fmaxf(a2, q2);
        const float mm4 = mm2*mm2;
        accU = fmaf(mm4, mm4, accU);
    };

    // Software-pipelined weight fetch: load c+1's 6 float4 while computing c.
    float4 cA0 = wbA[0], cA1 = wbA[1], cA2 = wbA[2];
    float4 cB0 = wbB[0], cB1 = wbB[1], cB2 = wbB[2];

    for (int c = 0; c < CHALF; ++c) {
        const int cn = (c < CHALF-1) ? c + 1 : c;
        const float4 nA0 = wbA[cn*3+0], nA1 = wbA[cn*3+1], nA2 = wbA[cn*3+2];
        const float4 nB0 = wbB[cn*3+0], nB1 = wbB[cn*3+1], nB2 = wbB[cn*3+2];

        const int pb = c*102 + tx;
        const float4 p00 = sP[pb +  0], p01 = sP[pb +  1], p02 = sP[pb +  2];
        const float4 p10 = sP[pb + 34], p11 = sP[pb + 35], p12 = sP[pb + 36];
        const float4 p20 = sP[pb + 68], p21 = sP[pb + 69], p22 = sP[pb + 70];

        tap(cA0.x, p00, aY0, aL0, aU0); tap(cA0.y, p01, aY0, aL0, aU0); tap(cA0.z, p02, aY0, aL0, aU0);
        tap(cB0.x, p00, aY1, aL1, aU1); tap(cB0.y, p01, aY1, aL1, aU1); tap(cB0.z, p02, aY1, aL1, aU1);
        tap(cA1.x, p10, aY0, aL0, aU0); tap(cA1.y, p11, aY0, aL0, aU0); tap(cA1.z, p12, aY0, aL0, aU0);
        tap(cB1.x, p10, aY1, aL1, aU1); tap(cB1.y, p11, aY1, aL1, aU1); tap(cB1.z, p12, aY1, aL1, aU1);
        tap(cA2.x, p20, aY0, aL0, aU0); tap(cA2.y, p21, aY0, aL0, aU0); tap(cA2.z, p22, aY0, aL0, aU0);
        tap(cB2.x, p20, aY1, aL1, aU1); tap(cB2.y, p21, aY1, aL1, aU1); tap(cB2.z, p22, aY1, aL1, aU1);

        cA0 = nA0; cA1 = nA1; cA2 = nA2;
        cB0 = nB0; cB1 = nB1; cB2 = nB2;
    }

    const int o0 = ((b*NC + co0)*NH + h)*NW + tx;
    const int o1 = o0 + 8*NH*NW;
    pY[chalf*PLANE + o0] = aY0;
    pL[chalf*PLANE + o0] = aL0;
    pU[chalf*PLANE + o0] = aU0;
    pY[chalf*PLANE + o1] = aY1;
    pL[chalf*PLANE + o1] = aL1;
    pU[chalf*PLANE + o1] = aU1;
}

// Combine conv2 halves, eighth-root, add residual, relu, write out. float4-vectorized.
__global__ __launch_bounds__(256) void epilogue_k(
    const float* __restrict__ pY, const float* __restrict__ pL, const float* __restrict__ pU,
    const float* __restrict__ x,  const float* __restrict__ l,  const float* __restrict__ u,
    float* __restrict__ out)
{
    const int i = blockIdx.x*256 + threadIdx.x;     // float4 index, PLANE/4 total
    const float4* pY4 = (const float4*)pY;
    const float4* pL4 = (const float4*)pL;
    const float4* pU4 = (const float4*)pU;
    const float4* x4  = (const float4*)x;
    const float4* l4  = (const float4*)l;
    const float4* u4  = (const float4*)u;
    float4* out4 = (float4*)out;
    const int Q = PLANE/4;

    const float4 ya = pY4[i], yb = pY4[Q + i];
    const float4 la = pL4[i], lb = pL4[Q + i];
    const float4 ua = pU4[i], ub = pU4[Q + i];
    const float4 xr = x4[i], lr = l4[i], ur = u4[i];

    float4 oy, ol, ou;
    oy.x = fmaxf(s3(ya.x + yb.x) + xr.x, 0.0f);
    oy.y = fmaxf(s3(ya.y + yb.y) + xr.y, 0.0f);
    oy.z = fmaxf(s3(ya.z + yb.z) + xr.z, 0.0f);
    oy.w = fmaxf(s3(ya.w + yb.w) + xr.w, 0.0f);
    ol.x = fmaxf(s3(la.x + lb.x) + lr.x, 0.0f);
    ol.y = fmaxf(s3(la.y + lb.y) + lr.y, 0.0f);
    ol.z = fmaxf(s3(la.z + lb.z) + lr.z, 0.0f);
    ol.w = fmaxf(s3(la.w + lb.w) + lr.w, 0.0f);
    ou.x = fmaxf(s3(ua.x + ub.x) + ur.x, 0.0f);
    ou.y = fmaxf(s3(ua.y + ub.y) + ur.y, 0.0f);
    ou.z = fmaxf(s3(ua.z + ub.z) + ur.z, 0.0f);
    ou.w = fmaxf(s3(ua.w + ub.w) + ur.w, 0.0f);

    out4[i]       = oy;
    out4[Q + i]   = ol;
    out4[2*Q + i] = ou;
}

extern "C" void kernel_launch(void* const* d_in, const int* in_sizes, int n_in,
                              void* d_out, int out_size, void* d_ws, size_t ws_size,
                              hipStream_t stream)
{
    const float* x  = (const float*)d_in[0];
    const float* l  = (const float*)d_in[1];
    const float* u  = (const float*)d_in[2];
    const float* w1 = (const float*)d_in[3];
    const float* w2 = (const float*)d_in[4];
    float* ws  = (float*)d_ws;
    float* wf1 = ws;                        // 12288 floats (padded float4 layout)
    float* wf2 = wf1 + 12288;
    float* p1Y = wf2 + 12288;               // conv1 partials: [2][PLANE] each
    float* p1L = p1Y + 2*PLANE;
    float* p1U = p1L + 2*PLANE;
    float* p2Y = p1U + 2*PLANE;             // conv2 partials
    float* p2L = p2Y + 2*PLANE;
    float* p2U = p2L + 2*PLANE;
    float* out = (float*)d_out;

    prep_weights_k<<<64, 256, 0, stream>>>(w1, w2, wf1, wf2);

    dim3 blk(32, 8);
    dim3 grd(NH, 4, NB);                    // h, cog*2+chalf, b  -> 512 blocks
    normdist_conv_k<false><<<grd, blk, 0, stream>>>(x, l, u, wf1, p1Y, p1L, p1U);
    normdist_conv_k<true ><<<grd, blk, 0, stream>>>(p1Y, p1L, p1U, wf2, p2Y, p2L, p2U);
    epilogue_k<<<PLANE/1024, 256, 0, stream>>>(p2Y, p2L, p2U, x, l, u, out);
}